// Round 10
// baseline (1031.965 us; speedup 1.0000x reference)
//
#include <hip/hip_runtime.h>
#include <hip/hip_bf16.h>
#include <stdint.h>

typedef short bf16x8 __attribute__((ext_vector_type(8)));
typedef float f32x4 __attribute__((ext_vector_type(4)));

#define DI __device__ __forceinline__

DI unsigned short f2bf(float f) {
    return __builtin_bit_cast(unsigned short, __float2bfloat16(f));
}

DI f32x4 mfma16(bf16x8 a, bf16x8 b, f32x4 c) {
    return __builtin_amdgcn_mfma_f32_16x16x32_bf16(a, b, c, 0, 0, 0);
}

DI void gload16(const unsigned short* g, unsigned short* l) {
    __builtin_amdgcn_global_load_lds(
        (const __attribute__((address_space(1))) unsigned int*)g,
        (__attribute__((address_space(3))) unsigned int*)l, 16, 0, 0);
}

DI float gelu_f(float hv) {
    float y = 0.7978845608028654f * (hv + 0.044715f * hv * hv * hv);
    float th = 1.0f - 2.0f / (__expf(2.0f * y) + 1.0f);
    return 0.5f * hv * (1.0f + th);
}

// Round barrier: vmcnt(0) waits only loads issued >=1 full round ago (~free),
// raw s_barrier, sched fence so ds_reads don't hoist above it (rule #18).
#define RSYNC() do { asm volatile("s_waitcnt vmcnt(0)" ::: "memory"); \
    __builtin_amdgcn_s_barrier(); __builtin_amdgcn_sched_barrier(0); } while (0)

// ---------------------------------------------------------------------------
// Prep: f32 weights -> bf16 B-fragment tiles in round order. (R3-verified)
// ---------------------------------------------------------------------------
__global__ __launch_bounds__(256)
void prep_kernel(const float* __restrict__ qkv_w, const float* __restrict__ proj_w,
                 const float* __restrict__ fc1_w, const float* __restrict__ fc2_w,
                 unsigned short* __restrict__ out)
{
    __shared__ float tileA[256][17];
    __shared__ float tileB[32][129];
    const int tid = threadIdx.x;
    const int tgl = blockIdx.x;           // 0..767
    const int layer = tgl / 192;
    const int tl = tgl % 192;
    bool kindA; const float* W; int ldN = 0, src_n16 = 0, strip = 0, ctb = 0;
    if (tl < 64) {
        int h = tl >> 3, u = tl & 7;
        if (u < 6) { kindA = true;  W = qkv_w + (size_t)layer * 256 * 768; ldN = 768;
                     src_n16 = (u >> 1) * 16 + 2 * h + (u & 1); }
        else       { kindA = false; W = proj_w + (size_t)layer * 256 * 256; ldN = 256;
                     strip = 32 * h; ctb = (u - 6) * 8; }
    } else {
        int q = tl - 64, rp = q >> 2, v = q & 3;
        if (v < 2) { kindA = true;  W = fc1_w + (size_t)layer * 256 * 1024; ldN = 1024;
                     src_n16 = 2 * rp + v; }
        else       { kindA = false; W = fc2_w + (size_t)layer * 1024 * 256; ldN = 256;
                     strip = 32 * rp; ctb = (v - 2) * 8; }
    }
    if (kindA) {
        const int cn = tid & 15, k0 = tid >> 4;
        const float* src = W + src_n16 * 16 + cn;
        #pragma unroll
        for (int p = 0; p < 16; ++p) {
            int kk = p * 16 + k0;
            tileA[kk][cn] = src[(size_t)kk * ldN];
        }
    } else {
        const int kk = tid >> 3, c0 = (tid & 7) * 16;
        const float* src = W + (size_t)(strip + kk) * ldN + ctb * 16 + c0;
        #pragma unroll
        for (int j = 0; j < 16; ++j) tileB[kk][c0 + j] = src[j];
    }
    __syncthreads();
    unsigned short* dst = out + (size_t)tgl * 4096;
    {
        int e0 = tid * 16;
        int s = e0 >> 9;
        int l = (e0 >> 3) & 63;
        union { unsigned short u[8]; bf16x8 v; } pk;
        if (kindA) {
            int kb = 32 * s + 8 * (l >> 4);
            int n = l & 15;
            #pragma unroll
            for (int i = 0; i < 8; ++i) pk.u[i] = f2bf(tileA[kb + i][n]);
        } else {
            int kb = 8 * (l >> 4);
            int cc = s * 16 + (l & 15);
            #pragma unroll
            for (int i = 0; i < 8; ++i) pk.u[i] = f2bf(tileB[kb + i][cc]);
        }
        *(bf16x8*)(dst + e0) = pk.v;
        int e1 = e0 + 8;
        int s1 = e1 >> 9;
        int l1 = (e1 >> 3) & 63;
        union { unsigned short u[8]; bf16x8 v; } pk1;
        if (kindA) {
            int kb = 32 * s1 + 8 * (l1 >> 4);
            int n = l1 & 15;
            #pragma unroll
            for (int i = 0; i < 8; ++i) pk1.u[i] = f2bf(tileA[kb + i][n]);
        } else {
            int kb = 8 * (l1 >> 4);
            int cc = s1 * 16 + (l1 & 15);
            #pragma unroll
            for (int i = 0; i < 8; ++i) pk1.u[i] = f2bf(tileB[kb + i][cc]);
        }
        *(bf16x8*)(dst + e1) = pk1.v;
    }
}

// ====================== named-register macro machinery ======================
#define CAT_(a, b) a##b
#define CAT(a, b) CAT_(a, b)

#define F8N(F)      F(0)F(1)F(2)F(3)F(4)F(5)F(6)F(7)
#define F16N(F)     F(0)F(1)F(2)F(3)F(4)F(5)F(6)F(7)F(8)F(9)F(10)F(11)F(12)F(13)F(14)F(15)
#define F8A(F,a)    F(0,a)F(1,a)F(2,a)F(3,a)F(4,a)F(5,a)F(6,a)F(7,a)
#define F8H(F,a)    F(8,a)F(9,a)F(10,a)F(11,a)F(12,a)F(13,a)F(14,a)F(15,a)
#define F16A(F,a)   F8A(F,a) F8H(F,a)
#define F8B(F,a,b)  F(0,a,b)F(1,a,b)F(2,a,b)F(3,a,b)F(4,a,b)F(5,a,b)F(6,a,b)F(7,a,b)
#define F16C(F,a,b) F8B(F,a,b) F(8,a,b)F(9,a,b)F(10,a,b)F(11,a,b)F(12,a,b)F(13,a,b)F(14,a,b)F(15,a,b)
#define F16D(F,a,b,c) F(0,a,b,c)F(1,a,b,c)F(2,a,b,c)F(3,a,b,c)F(4,a,b,c)F(5,a,b,c)F(6,a,b,c)F(7,a,b,c)F(8,a,b,c)F(9,a,b,c)F(10,a,b,c)F(11,a,b,c)F(12,a,b,c)F(13,a,b,c)F(14,a,b,c)F(15,a,b,c)

#define DECLX(n)  f32x4 CAT(xA,n);
#define DECLAV(s) bf16x8 CAT(avA,s);

// --- embedding ---
#define EMB_N(n, P, R) { const int col = (n)*16 + lq; float e = 0.f;            \
    if (sl_) e = o0_*W_slide[col] + o1_*W_slide[256+col] + b_slide[col];        \
    else if (hi_) e = o0_*W_hinge[col] + o1_*W_hinge[256+col]                   \
                    + o2_*W_hinge[512+col] + b_hinge[col];                      \
    else if (gl_) e = b_global[m*256+col]                                       \
        + o0_*W_global[(m*5+0)*256+col] + o1_*W_global[(m*5+1)*256+col]         \
        + o2_*W_global[(m*5+2)*256+col] + o3_*W_global[(m*5+3)*256+col]         \
        + o4_*W_global[(m*5+4)*256+col];                                        \
    if (am_) e += W_act[col];                                                   \
    e += pos_emb[pb_ + col];                                                    \
    CAT(CAT(x,P),n)[R] = e; }

#define EMB_ROW(R, G, P) { const int j_ = lg*4 + (R);                           \
    const size_t tok_ = (size_t)(G)*16 + j_;                                    \
    const float* ob_ = obs + tok_*16;                                           \
    const float o0_=ob_[0], o1_=ob_[1], o2_=ob_[2], o3_=ob_[3], o4_=ob_[4];     \
    const int sl_=slide_m[tok_], hi_=hinge_m[tok_];                             \
    const int gl_=global_m[tok_]&&hg; const int am_=act_m[tok_];                \
    const size_t pb_ = ((size_t)m*16+j_)*256;                                   \
    F16C(EMB_N, P, R) }

#define EMBED(G, P) { EMB_ROW(0,G,P) EMB_ROW(1,G,P) EMB_ROW(2,G,P) EMB_ROW(3,G,P) }

// --- layernorm ---
#define LNS_N(n, P) { f32x4 v4_ = CAT(CAT(x,P),n);                              \
    sm0+=v4_[0]; sq0+=v4_[0]*v4_[0]; sm1+=v4_[1]; sq1+=v4_[1]*v4_[1];           \
    sm2+=v4_[2]; sq2+=v4_[2]*v4_[2]; sm3+=v4_[3]; sq3+=v4_[3]*v4_[3]; }

#define RED4(v) { v+=__shfl_xor(v,1,64); v+=__shfl_xor(v,2,64);                 \
                  v+=__shfl_xor(v,4,64); v+=__shfl_xor(v,8,64); }

#define LNW_N(n, P) { const float wv_=lw_[(n)*16+lq], lbv_=lb_[(n)*16+lq];      \
    const int t16_=(2*(n)+(lq>>3))&3; const int base_=(((n)&7)>>1)*512+(lq&7);  \
    slotA[base_+(4*lg+0+16*t16_)*8] = f2bf((CAT(CAT(x,P),n)[0]-mu0)*rs0*wv_+lbv_); \
    slotA[base_+(4*lg+1+16*t16_)*8] = f2bf((CAT(CAT(x,P),n)[1]-mu1)*rs1*wv_+lbv_); \
    slotA[base_+(4*lg+2+16*t16_)*8] = f2bf((CAT(CAT(x,P),n)[2]-mu2)*rs2*wv_+lbv_); \
    slotA[base_+(4*lg+3+16*t16_)*8] = f2bf((CAT(CAT(x,P),n)[3]-mu3)*rs3*wv_+lbv_); }

#define LAYER_NORM(LW, LB, P) do {                                              \
    const float* lw_ = (LW); const float* lb_ = (LB);                           \
    float sm0=0,sm1=0,sm2=0,sm3=0, sq0=0,sq1=0,sq2=0,sq3=0;                     \
    F16A(LNS_N, P)                                                              \
    RED4(sm0) RED4(sm1) RED4(sm2) RED4(sm3)                                     \
    RED4(sq0) RED4(sq1) RED4(sq2) RED4(sq3)                                     \
    const float mu0=sm0*(1.f/256.f), mu1=sm1*(1.f/256.f);                       \
    const float mu2=sm2*(1.f/256.f), mu3=sm3*(1.f/256.f);                       \
    const float rs0=rsqrtf(sq0*(1.f/256.f)-mu0*mu0+1e-5f);                      \
    const float rs1=rsqrtf(sq1*(1.f/256.f)-mu1*mu1+1e-5f);                      \
    const float rs2=rsqrtf(sq2*(1.f/256.f)-mu2*mu2+1e-5f);                      \
    const float rs3=rsqrtf(sq3*(1.f/256.f)-mu3*mu3+1e-5f);                      \
    F8A(LNW_N, P)                                                               \
    CAT(CAT(av,P),0) = *(const bf16x8*)(slotA + 0*512 + lane*8);                \
    CAT(CAT(av,P),1) = *(const bf16x8*)(slotA + 1*512 + lane*8);                \
    CAT(CAT(av,P),2) = *(const bf16x8*)(slotA + 2*512 + lane*8);                \
    CAT(CAT(av,P),3) = *(const bf16x8*)(slotA + 3*512 + lane*8);                \
    F8H(LNW_N, P)                                                               \
    CAT(CAT(av,P),4) = *(const bf16x8*)(slotA + 0*512 + lane*8);                \
    CAT(CAT(av,P),5) = *(const bf16x8*)(slotA + 1*512 + lane*8);                \
    CAT(CAT(av,P),6) = *(const bf16x8*)(slotA + 2*512 + lane*8);                \
    CAT(CAT(av,P),7) = *(const bf16x8*)(slotA + 3*512 + lane*8);                \
} while (0)

// --- K=256 MFMA chain split into even/odd accumulators (ILP) ---
#define MFKE(s, BUFK, TT) { ae = mfma16(CAT(avA,s), bfrag((BUFK),(TT),(s)), ae); }
#define MFKO(s, BUFK, TT) { aod = mfma16(CAT(avA,s), bfrag((BUFK),(TT),(s)), aod); }
#define MFK8(BUFK, TT) MFKE(0,BUFK,TT) MFKO(1,BUFK,TT) MFKE(2,BUFK,TT) MFKO(3,BUFK,TT) \
                       MFKE(4,BUFK,TT) MFKO(5,BUFK,TT) MFKE(6,BUFK,TT) MFKO(7,BUFK,TT)

// --- flash fold: strip round holds 2 tiles x 8 frags = 16 col tiles ---
#define FOLD_CT(ct, BUFK, OFS, OF) {                                            \
    bf16x8 bq_ = bfrag((BUFK), (ct)>>3, (ct)&7);                                \
    const float ls_ = ls_lds[(OFS)+(ct)*16+lq];                                 \
    f32x4 p0_ = mfma16((OF), bq_, zf);                                          \
    CAT(xA,ct)[0]+=ls_*p0_[0]; CAT(xA,ct)[1]+=ls_*p0_[1];                       \
    CAT(xA,ct)[2]+=ls_*p0_[2]; CAT(xA,ct)[3]+=ls_*p0_[3]; }

#define ADDB_N(n, OFS, BP) { const float d_ = ls_lds[(OFS)+(n)*16+lq]*(BP)[(n)*16+lq]; \
    CAT(xA,n)[0]+=d_; CAT(xA,n)[1]+=d_; CAT(xA,n)[2]+=d_; CAT(xA,n)[3]+=d_; }

#define STORE_N(n) {                                                            \
    op0[(lg*4+0)*256+(n)*16+lq]=CAT(xA,n)[0]; op0[(lg*4+1)*256+(n)*16+lq]=CAT(xA,n)[1]; \
    op0[(lg*4+2)*256+(n)*16+lq]=CAT(xA,n)[2]; op0[(lg*4+3)*256+(n)*16+lq]=CAT(xA,n)[3]; }

// ---------------------------------------------------------------------------
// Fused kernel: 512 blocks x 512 threads (8 waves), 1 group/wave.
// 2-tile rounds, 2 staging buffers, depth-1 prefetch, counted-sync rounds.
// LDS = 79872 B <= 80 KB  ->  2 blocks/CU = 16 waves/CU (2x occupancy), and
// all 512 blocks co-resident (single generation, no tail).
// ---------------------------------------------------------------------------
__global__ __launch_bounds__(512)
void fused_kernel(const float* __restrict__ obs, const int* __restrict__ slide_m,
                  const int* __restrict__ hinge_m, const int* __restrict__ global_m,
                  const int* __restrict__ act_m, const int* __restrict__ morph_m,
                  const int* __restrict__ m_idx, const int* __restrict__ has_g,
                  const float* __restrict__ W_slide, const float* __restrict__ b_slide,
                  const float* __restrict__ W_hinge, const float* __restrict__ b_hinge,
                  const float* __restrict__ W_global, const float* __restrict__ b_global,
                  const float* __restrict__ W_act, const float* __restrict__ pos_emb,
                  const float* __restrict__ ln1_w, const float* __restrict__ ln1_b,
                  const float* __restrict__ qkv_b, const float* __restrict__ proj_b,
                  const float* __restrict__ ln2_w, const float* __restrict__ ln2_b,
                  const float* __restrict__ fc1_b, const float* __restrict__ fc2_b,
                  const float* __restrict__ ls1, const float* __restrict__ ls2,
                  const unsigned short* __restrict__ wsb, float* __restrict__ out)
{
    __shared__ __align__(16) unsigned char smem[79872];
    unsigned short* dbuf = (unsigned short*)smem;            // 32768 B: 2 bufs x 2 tiles
    float* ls_lds = (float*)(smem + 32768);                  // 2048 B (per-layer ls1|ls2)
    float* bias_lds = (float*)(smem + 34816);                // 1024 B (morph bias)
    float* biasbuf = (float*)(smem + 35840);                 // 7168 B: qkv_b[768]+fc1_b[1024]
    const int tid = threadIdx.x;
    const int w = tid >> 6, lane = tid & 63, lq = lane & 15, lg = lane >> 4;
    unsigned char* pw = smem + 43008 + w * 4608;
    unsigned short* slotA = (unsigned short*)pw;             // 4096 B (aliases qp/ks/vT)
    unsigned short* qp = (unsigned short*)pw;                // [16][36] 1152 B
    unsigned short* ks = (unsigned short*)(pw + 1152);       // [16][36] 1152 B
    unsigned short* vT = (unsigned short*)(pw + 2304);       // [32][36] 2304 B

    const int G = blockIdx.x * 8 + w;
    const int b = blockIdx.x >> 4;        // uniform per block
    const int m = m_idx[b];
    const int hg = has_g[m];

    auto bfrag = [&](int bufk, int tt, int s) -> bf16x8 {
        return *(const bf16x8*)(dbuf + bufk * 8192 + tt * 4096 + s * 512 + lane * 8);
    };
    auto stage2t = [&](int ri) {  // stage round ri's 2 tiles (16 KB) into buf[ri&1]
        const unsigned short* src = wsb + (size_t)ri * 8192 + tid * 8;
        unsigned short* dst = dbuf + (ri & 1) * 8192 + tid * 8;
        gload16(src, dst);
        gload16(src + 4096, dst + 4096);
    };

    stage2t(0);                   // in flight during embed
    if (tid < 256) bias_lds[tid] = morph_m[b * 256 + tid] ? 0.0f : -1e9f;

    F16N(DECLX)
    F8N(DECLAV)

    EMBED(G, A)

    const float SCALE = 0.17677669529663687f;  // 32^-0.5
    const f32x4 zf = {0.f, 0.f, 0.f, 0.f};

    auto attn = [&]() -> bf16x8 {
        bf16x8 kf = *(const bf16x8*)(ks + lq * 36 + lg * 8);
        bf16x8 qf = *(const bf16x8*)(qp + lq * 36 + lg * 8);
        f32x4 st = mfma16(kf, qf, zf);     // row=key=4lg+rr, col=query=lq
        float p0 = st[0] * SCALE + bias_lds[lq * 16 + 4 * lg + 0];
        float p1 = st[1] * SCALE + bias_lds[lq * 16 + 4 * lg + 1];
        float p2 = st[2] * SCALE + bias_lds[lq * 16 + 4 * lg + 2];
        float p3 = st[3] * SCALE + bias_lds[lq * 16 + 4 * lg + 3];
        float mx = fmaxf(fmaxf(p0, p1), fmaxf(p2, p3));
        mx = fmaxf(mx, __shfl_xor(mx, 16, 64));
        mx = fmaxf(mx, __shfl_xor(mx, 32, 64));
        p0 = __expf(p0 - mx); p1 = __expf(p1 - mx);
        p2 = __expf(p2 - mx); p3 = __expf(p3 - mx);
        float ps = p0 + p1 + p2 + p3;
        ps += __shfl_xor(ps, 16, 64);
        ps += __shfl_xor(ps, 32, 64);
        float inv = 1.f / ps;
        qp[lq * 36 + lg * 4 + 0] = f2bf(p0 * inv);
        qp[lq * 36 + lg * 4 + 1] = f2bf(p1 * inv);
        qp[lq * 36 + lg * 4 + 2] = f2bf(p2 * inv);
        qp[lq * 36 + lg * 4 + 3] = f2bf(p3 * inv);
        qp[lq * 36 + 16 + lg * 4 + 0] = 0;
        qp[lq * 36 + 16 + lg * 4 + 1] = 0;
        qp[lq * 36 + 16 + lg * 4 + 2] = 0;
        qp[lq * 36 + 16 + lg * 4 + 3] = 0;
        bf16x8 pf = *(const bf16x8*)(qp + lq * 36 + lg * 8);
        f32x4 o0 = mfma16(pf, *(const bf16x8*)(vT + lq * 36 + lg * 8), zf);
        f32x4 o1 = mfma16(pf, *(const bf16x8*)(vT + (16 + lq) * 36 + lg * 8), zf);
        #pragma unroll
        for (int rr = 0; rr < 4; ++rr) {
            ks[((4 * lg + rr) + 16 * ((lq >> 3) & 3)) * 8 + (lq & 7)] = f2bf(o0[rr]);
            ks[((4 * lg + rr) + 16 * ((2 + (lq >> 3)) & 3)) * 8 + (lq & 7)] = f2bf(o1[rr]);
        }
        return *(const bf16x8*)(ks + lane * 8);
    };

    for (int layer = 0; layer < 4; ++layer) {
        __syncthreads();   // prev-layer table readers done (4x/kernel, drains ok)
        ls_lds[tid] = (tid < 256) ? ls1[layer * 256 + tid] : ls2[layer * 256 + tid - 256];
        for (int i = tid; i < 1792; i += 512)
            biasbuf[i] = (i < 768) ? qkv_b[layer * 768 + i]
                                   : fc1_b[layer * 1024 + i - 768];
        __syncthreads();   // tables visible

        // ===== LN1 =====
        LAYER_NORM(ln1_w + layer * 256, ln1_b + layer * 256, A);
        // re-zero vT pad (LN clobbered aliased region; av already in regs)
        #pragma unroll
        for (int ii = 0; ii < 8; ++ii) {
            int idx = ii * 64 + lane;
            vT[(idx >> 4) * 36 + 16 + (idx & 15)] = 0;
        }
        // pre-add ls1*proj_b
        { const float* pbp_ = proj_b + layer * 256; F16C(ADDB_N, 0, pbp_) }

        // ===== attention phase: 32 rounds (q | k | v | strip per head) =====
        for (int r = 0; r < 32; ++r) {
            const int rg = layer * 96 + r;
            RSYNC();
            if (rg + 1 < 384) stage2t(rg + 1);
            const int bufk = rg & 1;
            const int h = r >> 2, ph = r & 3;
            if (ph < 3) {
                #pragma unroll
                for (int tt = 0; tt < 2; ++tt) {
                    float bv = biasbuf[ph * 256 + (2 * h + tt) * 16 + lq];
                    f32x4 ae = {bv, bv, bv, bv}, aod = zf;
                    MFK8(bufk, tt)
                    f32x4 a0 = ae + aod;
                    if (ph == 0) {
                        #pragma unroll
                        for (int rr = 0; rr < 4; ++rr)
                            qp[(4 * lg + rr) * 36 + tt * 16 + lq] = f2bf(a0[rr]);
                    } else if (ph == 1) {
                        #pragma unroll
                        for (int rr = 0; rr < 4; ++rr)
                            ks[(4 * lg + rr) * 36 + tt * 16 + lq] = f2bf(a0[rr]);
                    } else {
                        #pragma unroll
                        for (int rr = 0; rr < 4; ++rr)
                            vT[(tt * 16 + lq) * 36 + 4 * lg + rr] = f2bf(a0[rr]);
                    }
                }
            } else {
                bf16x8 of = attn();
                F16D(FOLD_CT, bufk, 0, of)
            }
        }

        // ===== LN2 + ls2*fc2_b prefold =====
        LAYER_NORM(ln2_w + layer * 256, ln2_b + layer * 256, A);
        { const float* pbf_ = fc2_b + layer * 256; F16C(ADDB_N, 256, pbf_) }

        // ===== MLP phase: 64 rounds (fc1 pair / fc2 strip alternating) =====
        for (int r2 = 0; r2 < 64; ++r2) {
            const int rg = layer * 96 + 32 + r2;
            RSYNC();
            if (rg + 1 < 384) stage2t(rg + 1);
            const int bufk = rg & 1;
            if (!(r2 & 1)) {
                const int rp = r2 >> 1;
                #pragma unroll
                for (int tt = 0; tt < 2; ++tt) {
                    float bv = biasbuf[768 + (2 * rp + tt) * 16 + lq];
                    f32x4 ae = {bv, bv, bv, bv}, aod = zf;
                    MFK8(bufk, tt)
                    f32x4 a0 = ae + aod;
                    int t16 = (2 * tt + (lq >> 3)) & 3;
                    #pragma unroll
                    for (int rr = 0; rr < 4; ++rr)
                        ks[((4 * lg + rr) + 16 * t16) * 8 + (lq & 7)] = f2bf(gelu_f(a0[rr]));
                }
            } else {
                bf16x8 gf = *(const bf16x8*)(ks + lane * 8);
                F16D(FOLD_CT, bufk, 256, gf)
            }
        }
    }

    // ---- store ----
    float* op0 = out + (size_t)G * 4096;
    F16N(STORE_N)
}

extern "C" void kernel_launch(void* const* d_in, const int* in_sizes, int n_in,
                              void* d_out, int out_size, void* d_ws, size_t ws_size,
                              hipStream_t stream) {
    (void)in_sizes; (void)n_in; (void)out_size; (void)ws_size;
    const float* obs      = (const float*)d_in[0];
    const int*   slide_m  = (const int*)d_in[1];
    const int*   hinge_m  = (const int*)d_in[2];
    const int*   global_m = (const int*)d_in[3];
    const int*   act_m    = (const int*)d_in[4];
    const int*   morph_m  = (const int*)d_in[5];
    const int*   m_idx    = (const int*)d_in[6];
    const int*   has_g    = (const int*)d_in[7];
    const float* W_slide  = (const float*)d_in[8];
    const float* b_slide  = (const float*)d_in[9];
    const float* W_hinge  = (const float*)d_in[10];
    const float* b_hinge  = (const float*)d_in[11];
    const float* W_global = (const float*)d_in[12];
    const float* b_global = (const float*)d_in[13];
    const float* W_act    = (const float*)d_in[14];
    const float* pos_emb  = (const float*)d_in[15];
    const float* ln1_w    = (const float*)d_in[16];
    const float* ln1_b    = (const float*)d_in[17];
    const float* qkv_w    = (const float*)d_in[18];
    const float* qkv_b    = (const float*)d_in[19];
    const float* proj_w   = (const float*)d_in[20];
    const float* proj_b   = (const float*)d_in[21];
    const float* ln2_w    = (const float*)d_in[22];
    const float* ln2_b    = (const float*)d_in[23];
    const float* fc1_w    = (const float*)d_in[24];
    const float* fc1_b    = (const float*)d_in[25];
    const float* fc2_w    = (const float*)d_in[26];
    const float* fc2_b    = (const float*)d_in[27];
    const float* ls1      = (const float*)d_in[28];
    const float* ls2      = (const float*)d_in[29];
    unsigned short* wsb = (unsigned short*)d_ws;

    prep_kernel<<<768, 256, 0, stream>>>(qkv_w, proj_w, fc1_w, fc2_w, wsb);
    fused_kernel<<<512, 512, 0, stream>>>(obs, slide_m, hinge_m, global_m, act_m, morph_m,
        m_idx, has_g, W_slide, b_slide, W_hinge, b_hinge, W_global, b_global, W_act, pos_emb,
        ln1_w, ln1_b, qkv_b, proj_b, ln2_w, ln2_b, fc1_b, fc2_b, ls1, ls2, wsb, (float*)d_out);
}

// Round 11
// 769.429 us; speedup vs baseline: 1.3412x; 1.3412x over previous
//
#include <hip/hip_runtime.h>
#include <hip/hip_bf16.h>
#include <stdint.h>

typedef short bf16x8 __attribute__((ext_vector_type(8)));
typedef float f32x4 __attribute__((ext_vector_type(4)));

#define DI __device__ __forceinline__

DI unsigned short f2bf(float f) {
    return __builtin_bit_cast(unsigned short, __float2bfloat16(f));
}

DI f32x4 mfma16(bf16x8 a, bf16x8 b, f32x4 c) {
    return __builtin_amdgcn_mfma_f32_16x16x32_bf16(a, b, c, 0, 0, 0);
}

DI void gload16(const unsigned short* g, unsigned short* l) {
    __builtin_amdgcn_global_load_lds(
        (const __attribute__((address_space(1))) unsigned int*)g,
        (__attribute__((address_space(3))) unsigned int*)l, 16, 0, 0);
}

DI float gelu_f(float hv) {
    float y = 0.7978845608028654f * (hv + 0.044715f * hv * hv * hv);
    float th = 1.0f - 2.0f / (__expf(2.0f * y) + 1.0f);
    return 0.5f * hv * (1.0f + th);
}

// Light round barrier: counted vmcnt keeps next round's stage in flight.
#define RSYNC4() do { asm volatile("s_waitcnt vmcnt(4)" ::: "memory"); \
    __builtin_amdgcn_s_barrier(); __builtin_amdgcn_sched_barrier(0); } while (0)
#define RSYNC0() do { asm volatile("s_waitcnt vmcnt(0)" ::: "memory"); \
    __builtin_amdgcn_s_barrier(); __builtin_amdgcn_sched_barrier(0); } while (0)

// ---------------------------------------------------------------------------
// Prep: f32 weights -> bf16 B-fragment tiles in round order. (R3-verified)
// NEW: proj_w columns pre-scaled by ls1[col], fc2_w columns by ls2[col]
// (layer-scale folded into strip weights -> fused FOLD is a pure MFMA
// C-accumulate, no per-element VALU).
// ---------------------------------------------------------------------------
__global__ __launch_bounds__(256)
void prep_kernel(const float* __restrict__ qkv_w, const float* __restrict__ proj_w,
                 const float* __restrict__ fc1_w, const float* __restrict__ fc2_w,
                 const float* __restrict__ ls1, const float* __restrict__ ls2,
                 unsigned short* __restrict__ out)
{
    __shared__ float tileA[256][17];
    __shared__ float tileB[32][129];
    const int tid = threadIdx.x;
    const int tgl = blockIdx.x;           // 0..767
    const int layer = tgl / 192;
    const int tl = tgl % 192;
    bool kindA; const float* W; int ldN = 0, src_n16 = 0, strip = 0, ctb = 0;
    const float* lsp = nullptr;           // column scale for strip tiles
    if (tl < 64) {
        int h = tl >> 3, u = tl & 7;
        if (u < 6) { kindA = true;  W = qkv_w + (size_t)layer * 256 * 768; ldN = 768;
                     src_n16 = (u >> 1) * 16 + 2 * h + (u & 1); }
        else       { kindA = false; W = proj_w + (size_t)layer * 256 * 256; ldN = 256;
                     strip = 32 * h; ctb = (u - 6) * 8; lsp = ls1 + layer * 256; }
    } else {
        int q = tl - 64, rp = q >> 2, v = q & 3;
        if (v < 2) { kindA = true;  W = fc1_w + (size_t)layer * 256 * 1024; ldN = 1024;
                     src_n16 = 2 * rp + v; }
        else       { kindA = false; W = fc2_w + (size_t)layer * 1024 * 256; ldN = 256;
                     strip = 32 * rp; ctb = (v - 2) * 8; lsp = ls2 + layer * 256; }
    }
    if (kindA) {
        const int cn = tid & 15, k0 = tid >> 4;
        const float* src = W + src_n16 * 16 + cn;
        #pragma unroll
        for (int p = 0; p < 16; ++p) {
            int kk = p * 16 + k0;
            tileA[kk][cn] = src[(size_t)kk * ldN];
        }
    } else {
        const int kk = tid >> 3, c0 = (tid & 7) * 16;
        const float* src = W + (size_t)(strip + kk) * ldN + ctb * 16 + c0;
        #pragma unroll
        for (int j = 0; j < 16; ++j) tileB[kk][c0 + j] = src[j];
    }
    __syncthreads();
    unsigned short* dst = out + (size_t)tgl * 4096;
    {
        int e0 = tid * 16;
        int s = e0 >> 9;
        int l = (e0 >> 3) & 63;
        union { unsigned short u[8]; bf16x8 v; } pk;
        if (kindA) {
            int kb = 32 * s + 8 * (l >> 4);
            int n = l & 15;
            #pragma unroll
            for (int i = 0; i < 8; ++i) pk.u[i] = f2bf(tileA[kb + i][n]);
        } else {
            int kb = 8 * (l >> 4);
            int cc = s * 16 + (l & 15);
            const float sc = lsp[ctb * 16 + cc];
            #pragma unroll
            for (int i = 0; i < 8; ++i) pk.u[i] = f2bf(tileB[kb + i][cc] * sc);
        }
        *(bf16x8*)(dst + e0) = pk.v;
        int e1 = e0 + 8;
        int s1 = e1 >> 9;
        int l1 = (e1 >> 3) & 63;
        union { unsigned short u[8]; bf16x8 v; } pk1;
        if (kindA) {
            int kb = 32 * s1 + 8 * (l1 >> 4);
            int n = l1 & 15;
            #pragma unroll
            for (int i = 0; i < 8; ++i) pk1.u[i] = f2bf(tileA[kb + i][n]);
        } else {
            int kb = 8 * (l1 >> 4);
            int cc = s1 * 16 + (l1 & 15);
            const float sc = lsp[ctb * 16 + cc];
            #pragma unroll
            for (int i = 0; i < 8; ++i) pk1.u[i] = f2bf(tileB[kb + i][cc] * sc);
        }
        *(bf16x8*)(dst + e1) = pk1.v;
    }
}

// ====================== named-register macro machinery ======================
#define CAT_(a, b) a##b
#define CAT(a, b) CAT_(a, b)

#define F8N(F)      F(0)F(1)F(2)F(3)F(4)F(5)F(6)F(7)
#define F16N(F)     F(0)F(1)F(2)F(3)F(4)F(5)F(6)F(7)F(8)F(9)F(10)F(11)F(12)F(13)F(14)F(15)
#define F8A(F,a)    F(0,a)F(1,a)F(2,a)F(3,a)F(4,a)F(5,a)F(6,a)F(7,a)
#define F8H(F,a)    F(8,a)F(9,a)F(10,a)F(11,a)F(12,a)F(13,a)F(14,a)F(15,a)
#define F16A(F,a)   F8A(F,a) F8H(F,a)
#define F8B(F,a,b)  F(0,a,b)F(1,a,b)F(2,a,b)F(3,a,b)F(4,a,b)F(5,a,b)F(6,a,b)F(7,a,b)
#define F16C(F,a,b) F8B(F,a,b) F(8,a,b)F(9,a,b)F(10,a,b)F(11,a,b)F(12,a,b)F(13,a,b)F(14,a,b)F(15,a,b)
#define F16D(F,a,b,c) F(0,a,b,c)F(1,a,b,c)F(2,a,b,c)F(3,a,b,c)F(4,a,b,c)F(5,a,b,c)F(6,a,b,c)F(7,a,b,c)F(8,a,b,c)F(9,a,b,c)F(10,a,b,c)F(11,a,b,c)F(12,a,b,c)F(13,a,b,c)F(14,a,b,c)F(15,a,b,c)

#define DECLX(n)  f32x4 CAT(xA,n);
#define DECLAV(s) bf16x8 CAT(avA,s);

// --- embedding ---
#define EMB_N(n, P, R) { const int col = (n)*16 + lq; float e = 0.f;            \
    if (sl_) e = o0_*W_slide[col] + o1_*W_slide[256+col] + b_slide[col];        \
    else if (hi_) e = o0_*W_hinge[col] + o1_*W_hinge[256+col]                   \
                    + o2_*W_hinge[512+col] + b_hinge[col];                      \
    else if (gl_) e = b_global[m*256+col]                                       \
        + o0_*W_global[(m*5+0)*256+col] + o1_*W_global[(m*5+1)*256+col]         \
        + o2_*W_global[(m*5+2)*256+col] + o3_*W_global[(m*5+3)*256+col]         \
        + o4_*W_global[(m*5+4)*256+col];                                        \
    if (am_) e += W_act[col];                                                   \
    e += pos_emb[pb_ + col];                                                    \
    CAT(CAT(x,P),n)[R] = e; }

#define EMB_ROW(R, G, P) { const int j_ = lg*4 + (R);                           \
    const size_t tok_ = (size_t)(G)*16 + j_;                                    \
    const float* ob_ = obs + tok_*16;                                           \
    const float o0_=ob_[0], o1_=ob_[1], o2_=ob_[2], o3_=ob_[3], o4_=ob_[4];     \
    const int sl_=slide_m[tok_], hi_=hinge_m[tok_];                             \
    const int gl_=global_m[tok_]&&hg; const int am_=act_m[tok_];                \
    const size_t pb_ = ((size_t)m*16+j_)*256;                                   \
    F16C(EMB_N, P, R) }

#define EMBED(G, P) { EMB_ROW(0,G,P) EMB_ROW(1,G,P) EMB_ROW(2,G,P) EMB_ROW(3,G,P) }

// --- layernorm ---
#define LNS_N(n, P) { f32x4 v4_ = CAT(CAT(x,P),n);                              \
    sm0+=v4_[0]; sq0+=v4_[0]*v4_[0]; sm1+=v4_[1]; sq1+=v4_[1]*v4_[1];           \
    sm2+=v4_[2]; sq2+=v4_[2]*v4_[2]; sm3+=v4_[3]; sq3+=v4_[3]*v4_[3]; }

#define RED4(v) { v+=__shfl_xor(v,1,64); v+=__shfl_xor(v,2,64);                 \
                  v+=__shfl_xor(v,4,64); v+=__shfl_xor(v,8,64); }

#define LNW_N(n, P) { const float wv_=lw_[(n)*16+lq], lbv_=lb_[(n)*16+lq];      \
    const int t16_=(2*(n)+(lq>>3))&3; const int base_=(((n)&7)>>1)*512+(lq&7);  \
    slotA[base_+(4*lg+0+16*t16_)*8] = f2bf((CAT(CAT(x,P),n)[0]-mu0)*rs0*wv_+lbv_); \
    slotA[base_+(4*lg+1+16*t16_)*8] = f2bf((CAT(CAT(x,P),n)[1]-mu1)*rs1*wv_+lbv_); \
    slotA[base_+(4*lg+2+16*t16_)*8] = f2bf((CAT(CAT(x,P),n)[2]-mu2)*rs2*wv_+lbv_); \
    slotA[base_+(4*lg+3+16*t16_)*8] = f2bf((CAT(CAT(x,P),n)[3]-mu3)*rs3*wv_+lbv_); }

#define LAYER_NORM(LW, LB, P) do {                                              \
    const float* lw_ = (LW); const float* lb_ = (LB);                           \
    float sm0=0,sm1=0,sm2=0,sm3=0, sq0=0,sq1=0,sq2=0,sq3=0;                     \
    F16A(LNS_N, P)                                                              \
    RED4(sm0) RED4(sm1) RED4(sm2) RED4(sm3)                                     \
    RED4(sq0) RED4(sq1) RED4(sq2) RED4(sq3)                                     \
    const float mu0=sm0*(1.f/256.f), mu1=sm1*(1.f/256.f);                       \
    const float mu2=sm2*(1.f/256.f), mu3=sm3*(1.f/256.f);                       \
    const float rs0=rsqrtf(sq0*(1.f/256.f)-mu0*mu0+1e-5f);                      \
    const float rs1=rsqrtf(sq1*(1.f/256.f)-mu1*mu1+1e-5f);                      \
    const float rs2=rsqrtf(sq2*(1.f/256.f)-mu2*mu2+1e-5f);                      \
    const float rs3=rsqrtf(sq3*(1.f/256.f)-mu3*mu3+1e-5f);                      \
    F8A(LNW_N, P)                                                               \
    CAT(CAT(av,P),0) = *(const bf16x8*)(slotA + 0*512 + lane*8);                \
    CAT(CAT(av,P),1) = *(const bf16x8*)(slotA + 1*512 + lane*8);                \
    CAT(CAT(av,P),2) = *(const bf16x8*)(slotA + 2*512 + lane*8);                \
    CAT(CAT(av,P),3) = *(const bf16x8*)(slotA + 3*512 + lane*8);                \
    F8H(LNW_N, P)                                                               \
    CAT(CAT(av,P),4) = *(const bf16x8*)(slotA + 0*512 + lane*8);                \
    CAT(CAT(av,P),5) = *(const bf16x8*)(slotA + 1*512 + lane*8);                \
    CAT(CAT(av,P),6) = *(const bf16x8*)(slotA + 2*512 + lane*8);                \
    CAT(CAT(av,P),7) = *(const bf16x8*)(slotA + 3*512 + lane*8);                \
} while (0)

// --- K=256 MFMA chain split into even/odd accumulators (ILP) ---
#define MFKE(s, BUFK, TT) { ae = mfma16(CAT(avA,s), bfrag((BUFK),(TT),(s)), ae); }
#define MFKO(s, BUFK, TT) { aod = mfma16(CAT(avA,s), bfrag((BUFK),(TT),(s)), aod); }
#define MFK8(BUFK, TT) MFKE(0,BUFK,TT) MFKO(1,BUFK,TT) MFKE(2,BUFK,TT) MFKO(3,BUFK,TT) \
                       MFKE(4,BUFK,TT) MFKO(5,BUFK,TT) MFKE(6,BUFK,TT) MFKO(7,BUFK,TT)

// --- flash fold: ls pre-folded into weights -> pure C-accumulate MFMA ---
#define FOLD_CT(ct, BUFK, OFS, OF) {                                            \
    bf16x8 bq_ = bfrag((BUFK), 2 + ((ct)>>3), (ct)&7);                          \
    CAT(xA,ct) = mfma16((OF), bq_, CAT(xA,ct)); }

#define ADDB_N(n, OFS, BP) { const float d_ = ls_lds[(OFS)+(n)*16+lq]*(BP)[(n)*16+lq]; \
    CAT(xA,n)[0]+=d_; CAT(xA,n)[1]+=d_; CAT(xA,n)[2]+=d_; CAT(xA,n)[3]+=d_; }

#define STORE_N(n) {                                                            \
    op0[(lg*4+0)*256+(n)*16+lq]=CAT(xA,n)[0]; op0[(lg*4+1)*256+(n)*16+lq]=CAT(xA,n)[1]; \
    op0[(lg*4+2)*256+(n)*16+lq]=CAT(xA,n)[2]; op0[(lg*4+3)*256+(n)*16+lq]=CAT(xA,n)[3]; }

// ---------------------------------------------------------------------------
// Fused kernel: 512 blocks x 512 threads (8 waves), 1 group/wave.
// R9 structure (4-tile rounds, 3-buf rotation, 2-deep prefetch, vmcnt(4)
// barriers) + ls-folded strip weights (FOLD = direct MFMA C-accumulate).
// ---------------------------------------------------------------------------
__global__ __launch_bounds__(512)
void fused_kernel(const float* __restrict__ obs, const int* __restrict__ slide_m,
                  const int* __restrict__ hinge_m, const int* __restrict__ global_m,
                  const int* __restrict__ act_m, const int* __restrict__ morph_m,
                  const int* __restrict__ m_idx, const int* __restrict__ has_g,
                  const float* __restrict__ W_slide, const float* __restrict__ b_slide,
                  const float* __restrict__ W_hinge, const float* __restrict__ b_hinge,
                  const float* __restrict__ W_global, const float* __restrict__ b_global,
                  const float* __restrict__ W_act, const float* __restrict__ pos_emb,
                  const float* __restrict__ ln1_w, const float* __restrict__ ln1_b,
                  const float* __restrict__ qkv_b, const float* __restrict__ proj_b,
                  const float* __restrict__ ln2_w, const float* __restrict__ ln2_b,
                  const float* __restrict__ fc1_b, const float* __restrict__ fc2_b,
                  const float* __restrict__ ls1, const float* __restrict__ ls2,
                  const unsigned short* __restrict__ wsb, float* __restrict__ out)
{
    __shared__ __align__(16) unsigned char smem[157696];
    unsigned short* dbuf = (unsigned short*)smem;            // 98304 B: 3 bufs x 4 tiles
    float* ls4 = (float*)(smem + 98304);                     // 8192 B: [layer][512]
    float* bias_lds = (float*)(smem + 106496);               // 1024 B (morph bias)
    float* biasbuf = (float*)(smem + 107520);                // 7168 B: qkv_b[768]+fc1_b[1024]
    const int tid = threadIdx.x;
    const int w = tid >> 6, lane = tid & 63, lq = lane & 15, lg = lane >> 4;
    unsigned char* pw = smem + 114688 + w * 5376;
    unsigned short* slotA = (unsigned short*)pw;             // 4096 B (aliases qp/ks/vT)
    unsigned short* qp = (unsigned short*)pw;                // [16][40]
    unsigned short* ks = (unsigned short*)(pw + 1280);       // [16][40]
    unsigned short* vT = (unsigned short*)(pw + 2560);       // [32][40]

    const int G = blockIdx.x * 8 + w;
    const int b = blockIdx.x >> 4;        // uniform per block
    const int m = m_idx[b];
    const int hg = has_g[m];

    if (tid < 256) bias_lds[tid] = morph_m[b * 256 + tid] ? 0.0f : -1e9f;
    #pragma unroll
    for (int l = 0; l < 4; ++l)
        ls4[l * 512 + tid] = (tid < 256) ? ls1[l * 256 + tid] : ls2[l * 256 + tid - 256];

    F16N(DECLX)
    F8N(DECLAV)

    EMBED(G, A)

    auto bfrag = [&](int bufk, int tt, int s) -> bf16x8 {
        return *(const bf16x8*)(dbuf + bufk * 16384 + tt * 4096 + s * 512 + lane * 8);
    };
    auto stage4 = [&](int ri) {   // stage round ri's 4 tiles into buf[ri%3]
        const unsigned short* src = wsb + (size_t)ri * 16384 + tid * 8;
        unsigned short* dst = dbuf + (ri % 3) * 16384 + tid * 8;
        gload16(src, dst);
        gload16(src + 4096, dst + 4096);
        gload16(src + 8192, dst + 8192);
        gload16(src + 12288, dst + 12288);
    };

    stage4(0);
    stage4(1);
    __syncthreads();   // ls4/bias_lds visible; stages 0,1 drained (once)

    const float SCALE = 0.17677669529663687f;  // 32^-0.5
    const f32x4 zf = {0.f, 0.f, 0.f, 0.f};

    auto attn = [&]() -> bf16x8 {
        bf16x8 kf = *(const bf16x8*)(ks + lq * 40 + lg * 8);
        bf16x8 qf = *(const bf16x8*)(qp + lq * 40 + lg * 8);
        f32x4 st = mfma16(kf, qf, zf);     // row=key=4lg+rr, col=query=lq
        float p0 = st[0] * SCALE + bias_lds[lq * 16 + 4 * lg + 0];
        float p1 = st[1] * SCALE + bias_lds[lq * 16 + 4 * lg + 1];
        float p2 = st[2] * SCALE + bias_lds[lq * 16 + 4 * lg + 2];
        float p3 = st[3] * SCALE + bias_lds[lq * 16 + 4 * lg + 3];
        float mx = fmaxf(fmaxf(p0, p1), fmaxf(p2, p3));
        mx = fmaxf(mx, __shfl_xor(mx, 16, 64));
        mx = fmaxf(mx, __shfl_xor(mx, 32, 64));
        p0 = __expf(p0 - mx); p1 = __expf(p1 - mx);
        p2 = __expf(p2 - mx); p3 = __expf(p3 - mx);
        float ps = p0 + p1 + p2 + p3;
        ps += __shfl_xor(ps, 16, 64);
        ps += __shfl_xor(ps, 32, 64);
        float inv = 1.f / ps;
        qp[lq * 40 + lg * 4 + 0] = f2bf(p0 * inv);
        qp[lq * 40 + lg * 4 + 1] = f2bf(p1 * inv);
        qp[lq * 40 + lg * 4 + 2] = f2bf(p2 * inv);
        qp[lq * 40 + lg * 4 + 3] = f2bf(p3 * inv);
        qp[lq * 40 + 16 + lg * 4 + 0] = 0;
        qp[lq * 40 + 16 + lg * 4 + 1] = 0;
        qp[lq * 40 + 16 + lg * 4 + 2] = 0;
        qp[lq * 40 + 16 + lg * 4 + 3] = 0;
        bf16x8 pf = *(const bf16x8*)(qp + lq * 40 + lg * 8);
        f32x4 o0 = mfma16(pf, *(const bf16x8*)(vT + lq * 40 + lg * 8), zf);
        f32x4 o1 = mfma16(pf, *(const bf16x8*)(vT + (16 + lq) * 40 + lg * 8), zf);
        #pragma unroll
        for (int rr = 0; rr < 4; ++rr) {
            ks[((4 * lg + rr) + 16 * ((lq >> 3) & 3)) * 8 + (lq & 7)] = f2bf(o0[rr]);
            ks[((4 * lg + rr) + 16 * ((2 + (lq >> 3)) & 3)) * 8 + (lq & 7)] = f2bf(o1[rr]);
        }
        return *(const bf16x8*)(ks + lane * 8);
    };

    for (int layer = 0; layer < 4; ++layer) {
        const float* ls_lds = ls4 + layer * 512;

        // layer tables: qkv_b + fc1_b into LDS (removes per-round global loads)
        for (int i = tid; i < 1792; i += 512)
            biasbuf[i] = (i < 768) ? qkv_b[layer * 768 + i]
                                   : fc1_b[layer * 1024 + i - 768];
        __syncthreads();   // layer-boundary full barrier (drains; 4x/kernel)

        // ===== LN1 =====
        LAYER_NORM(ln1_w + layer * 256, ln1_b + layer * 256, A);
        // re-zero vT pad (LN clobbered aliased region; av already in regs)
        #pragma unroll
        for (int ii = 0; ii < 8; ++ii) {
            int idx = ii * 64 + lane;
            vT[(idx >> 4) * 40 + 16 + (idx & 15)] = 0;
        }
        // pre-add ls1*proj_b
        { const float* pbp_ = proj_b + layer * 256; F16C(ADDB_N, 0, pbp_) }

        // ===== attention phase: 16 rounds (q+k | v+attn+strip per head) =====
        for (int r = 0; r < 16; ++r) {
            const int rg = layer * 48 + r;
            RSYNC4();
            if (rg + 2 <= 191) stage4(rg + 2);
            const int bufk = rg % 3;
            const int h = r >> 1;
            if (!(r & 1)) {
                // tiles: q0,q1,k0,k1
                #pragma unroll
                for (int tt = 0; tt < 4; ++tt) {
                    int sec = tt >> 1, nn = tt & 1;
                    float bv = biasbuf[sec * 256 + (2 * h + nn) * 16 + lq];
                    f32x4 ae = {bv, bv, bv, bv}, aod = zf;
                    MFK8(bufk, tt)
                    f32x4 a0 = ae + aod;
                    unsigned short* dstl = sec ? ks : qp;
                    #pragma unroll
                    for (int rr = 0; rr < 4; ++rr)
                        dstl[(4 * lg + rr) * 40 + nn * 16 + lq] = f2bf(a0[rr]);
                }
            } else {
                // tiles: v0,v1,p-strip0,p-strip1
                #pragma unroll
                for (int tt = 0; tt < 2; ++tt) {
                    float bv = biasbuf[512 + (2 * h + tt) * 16 + lq];
                    f32x4 ae = {bv, bv, bv, bv}, aod = zf;
                    MFK8(bufk, tt)
                    f32x4 a0 = ae + aod;
                    #pragma unroll
                    for (int rr = 0; rr < 4; ++rr)
                        vT[(tt * 16 + lq) * 40 + 4 * lg + rr] = f2bf(a0[rr]);
                }
                bf16x8 of = attn();
                F16D(FOLD_CT, bufk, 0, of)
            }
        }

        // ===== LN2 + ls2*fc2_b prefold =====
        LAYER_NORM(ln2_w + layer * 256, ln2_b + layer * 256, A);
        { const float* pbf_ = fc2_b + layer * 256; F16C(ADDB_N, 256, pbf_) }

        // ===== MLP phase: 32 rounds (fc1 pair + gelu + fc2 strip) =====
        for (int r2 = 0; r2 < 32; ++r2) {
            const int rg = layer * 48 + 16 + r2;
            if (rg == 191) { RSYNC0(); } else { RSYNC4(); }
            if (rg + 2 <= 191) stage4(rg + 2);
            const int bufk = rg % 3;
            #pragma unroll
            for (int tt = 0; tt < 2; ++tt) {
                float bv = biasbuf[768 + (2 * r2 + tt) * 16 + lq];
                f32x4 ae = {bv, bv, bv, bv}, aod = zf;
                MFK8(bufk, tt)
                f32x4 a0 = ae + aod;
                int t16 = (2 * tt + (lq >> 3)) & 3;
                #pragma unroll
                for (int rr = 0; rr < 4; ++rr)
                    ks[((4 * lg + rr) + 16 * t16) * 8 + (lq & 7)] = f2bf(gelu_f(a0[rr]));
            }
            bf16x8 gf = *(const bf16x8*)(ks + lane * 8);
            F16D(FOLD_CT, bufk, 256, gf)
        }
    }

    // ---- store ----
    float* op0 = out + (size_t)G * 4096;
    F16N(STORE_N)
}

extern "C" void kernel_launch(void* const* d_in, const int* in_sizes, int n_in,
                              void* d_out, int out_size, void* d_ws, size_t ws_size,
                              hipStream_t stream) {
    (void)in_sizes; (void)n_in; (void)out_size; (void)ws_size;
    const float* obs      = (const float*)d_in[0];
    const int*   slide_m  = (const int*)d_in[1];
    const int*   hinge_m  = (const int*)d_in[2];
    const int*   global_m = (const int*)d_in[3];
    const int*   act_m    = (const int*)d_in[4];
    const int*   morph_m  = (const int*)d_in[5];
    const int*   m_idx    = (const int*)d_in[6];
    const int*   has_g    = (const int*)d_in[7];
    const float* W_slide  = (const float*)d_in[8];
    const float* b_slide  = (const float*)d_in[9];
    const float* W_hinge  = (const float*)d_in[10];
    const float* b_hinge  = (const float*)d_in[11];
    const float* W_global = (const float*)d_in[12];
    const float* b_global = (const float*)d_in[13];
    const float* W_act    = (const float*)d_in[14];
    const float* pos_emb  = (const float*)d_in[15];
    const float* ln1_w    = (const float*)d_in[16];
    const float* ln1_b    = (const float*)d_in[17];
    const float* qkv_w    = (const float*)d_in[18];
    const float* qkv_b    = (const float*)d_in[19];
    const float* proj_w   = (const float*)d_in[20];
    const float* proj_b   = (const float*)d_in[21];
    const float* ln2_w    = (const float*)d_in[22];
    const float* ln2_b    = (const float*)d_in[23];
    const float* fc1_w    = (const float*)d_in[24];
    const float* fc1_b    = (const float*)d_in[25];
    const float* fc2_w    = (const float*)d_in[26];
    const float* fc2_b    = (const float*)d_in[27];
    const float* ls1      = (const float*)d_in[28];
    const float* ls2      = (const float*)d_in[29];
    unsigned short* wsb = (unsigned short*)d_ws;

    prep_kernel<<<768, 256, 0, stream>>>(qkv_w, proj_w, fc1_w, fc2_w, ls1, ls2, wsb);
    fused_kernel<<<512, 512, 0, stream>>>(obs, slide_m, hinge_m, global_m, act_m, morph_m,
        m_idx, has_g, W_slide, b_slide, W_hinge, b_hinge, W_global, b_global, W_act, pos_emb,
        ln1_w, ln1_b, qkv_b, proj_b, ln2_w, ln2_b, fc1_b, fc2_b, ls1, ls2, wsb, (float*)d_out);
}